// Round 1
// baseline (1611.392 us; speedup 1.0000x reference)
//
#include <hip/hip_runtime.h>

#define NEG_SLOPE 0.2f

__device__ __forceinline__ float lrelu(float x) { return x > 0.f ? x : NEG_SLOPE * x; }

// order-preserving float->uint encoding for atomic max
__device__ __forceinline__ unsigned fenc(float x) {
    unsigned u = __float_as_uint(x);
    return (u & 0x80000000u) ? ~u : (u | 0x80000000u);
}
__device__ __forceinline__ float fdec(unsigned u) {
    return (u & 0x80000000u) ? __uint_as_float(u ^ 0x80000000u) : __uint_as_float(~u);
}

// ---------------------------------------------------------------------------
// K1: h = X @ W  (W staged in LDS), plus per-(node,head) logits
//     al_s = <h[n,head,:], a_src[head,:]>, al_d likewise.
// F = per-head width, OUT = 2*F. Each group of F consecutive lanes = one
// (row, head); wave shfl_xor reduces the dot products.
// ---------------------------------------------------------------------------
template<int K, int F>
__global__ __launch_bounds__(256) void gemm_logits(
    const float* __restrict__ X, const float* __restrict__ W,
    const float* __restrict__ a_s, const float* __restrict__ a_d,
    float* __restrict__ Hout, float* __restrict__ als, float* __restrict__ ald,
    int n)
{
    constexpr int OUT = 2 * F;
    constexpr int ROWS = 256 / OUT;
    __shared__ float Wl[K * OUT];
    for (int i = threadIdx.x; i < K * OUT; i += 256) Wl[i] = W[i];
    __syncthreads();

    int r = blockIdx.x * ROWS + (int)threadIdx.x / OUT;
    int col = (int)threadIdx.x % OUT;
    if (r >= n) return;

    const float4* xr = (const float4*)(X + (size_t)r * K);
    float acc = 0.f;
#pragma unroll
    for (int k4 = 0; k4 < K / 4; ++k4) {
        float4 xv = xr[k4];
        acc = fmaf(xv.x, Wl[(4 * k4 + 0) * OUT + col], acc);
        acc = fmaf(xv.y, Wl[(4 * k4 + 1) * OUT + col], acc);
        acc = fmaf(xv.z, Wl[(4 * k4 + 2) * OUT + col], acc);
        acc = fmaf(xv.w, Wl[(4 * k4 + 3) * OUT + col], acc);
    }
    Hout[(size_t)r * OUT + col] = acc;

    float ps = acc * a_s[col];   // a_src flattened [H*F] == [OUT]
    float pd = acc * a_d[col];
#pragma unroll
    for (int off = F / 2; off > 0; off >>= 1) {
        ps += __shfl_xor(ps, off, 64);
        pd += __shfl_xor(pd, off, 64);
    }
    if ((col % F) == 0) {
        int head = col / F;
        als[r * 2 + head] = ps;
        ald[r * 2 + head] = pd;
    }
}

// ---------------------------------------------------------------------------
// K2: init per-(node,head) max with the self-loop source logit
// ---------------------------------------------------------------------------
__global__ __launch_bounds__(256) void node_init_max(
    const float* __restrict__ als, unsigned* __restrict__ maxb, int n2)
{
    int i = blockIdx.x * 256 + threadIdx.x;
    if (i < n2) maxb[i] = fenc(als[i]);
}

// ---------------------------------------------------------------------------
// K3: per-edge atomic max of al_s[src] into maxb[dst] (both heads)
// (leaky_relu monotone => max of e == lrelu(max al_s + al_d))
// ---------------------------------------------------------------------------
__global__ __launch_bounds__(256) void edge_max(
    const int* __restrict__ src, const int* __restrict__ dst,
    const float* __restrict__ als, unsigned* __restrict__ maxb, int E)
{
    int e = blockIdx.x * 256 + threadIdx.x;
    if (e >= E) return;
    int s = src[e], d = dst[e];
    atomicMax(&maxb[d * 2 + 0], fenc(als[s * 2 + 0]));
    atomicMax(&maxb[d * 2 + 1], fenc(als[s * 2 + 1]));
}

// ---------------------------------------------------------------------------
// K4: per (node,head): m = lrelu(max+al_d); self-loop term initializes
//     denom and the accumulator.  F lanes per group.
// ---------------------------------------------------------------------------
template<int F>
__global__ __launch_bounds__(256) void node_selfinit(
    const float* __restrict__ als, const float* __restrict__ ald,
    const unsigned* __restrict__ maxb, float* __restrict__ mbuf,
    float* __restrict__ denom, const float* __restrict__ Hbuf,
    float* __restrict__ acc, int n2)
{
    constexpr int GROUPS = 256 / F;
    int g = blockIdx.x * GROUPS + (int)threadIdx.x / F;
    int f = (int)threadIdx.x % F;
    if (g >= n2) return;
    float a_ld = ald[g];
    float m = lrelu(fdec(maxb[g]) + a_ld);
    float es = lrelu(als[g] + a_ld);
    float w = __expf(es - m) ;
    // use precise expf to stay close to reference
    w = expf(es - m);
    if (f == 0) { mbuf[g] = m; denom[g] = w; }
    acc[(size_t)g * F + f] = w * Hbuf[(size_t)g * F + f];
}

// ---------------------------------------------------------------------------
// K5: per edge, per head: w = exp(lrelu(al_s+al_d) - m[dst]);
//     denom[dst] += w;  acc[dst,head,:] += w * h[src,head,:]
//     F lanes per edge-group; both heads looped.
// ---------------------------------------------------------------------------
template<int F>
__global__ __launch_bounds__(256) void edge_scatter(
    const int* __restrict__ src, const int* __restrict__ dst,
    const float* __restrict__ als, const float* __restrict__ ald,
    const float* __restrict__ mbuf, float* __restrict__ denom,
    const float* __restrict__ Hbuf, float* __restrict__ acc, int E)
{
    constexpr int EDGES = 256 / F;
    int e = blockIdx.x * EDGES + (int)threadIdx.x / F;
    int f = (int)threadIdx.x % F;
    if (e >= E) return;
    int s = src[e], d = dst[e];
#pragma unroll
    for (int head = 0; head < 2; ++head) {
        int gs = s * 2 + head, gd = d * 2 + head;
        float el = lrelu(als[gs] + ald[gd]);
        float w = expf(el - mbuf[gd]);
        if (f == 0) atomicAdd(&denom[gd], w);
        atomicAdd(&acc[(size_t)gd * F + f], w * Hbuf[(size_t)gs * F + f]);
    }
}

// ---------------------------------------------------------------------------
// K6a: layers 1-2 finalize (in place): x = relu(acc/denom + b), OUT=128
// ---------------------------------------------------------------------------
__global__ __launch_bounds__(256) void finalize_relu(
    float* __restrict__ acc, const float* __restrict__ denom,
    const float* __restrict__ b, int total)   // total = n*128
{
    int idx = blockIdx.x * 256 + threadIdx.x;
    if (idx >= total) return;
    int col = idx & 127;
    int g = idx >> 6;                 // node*2 + head
    float v = acc[idx] / (denom[g] + 1e-16f) + b[col];
    acc[idx] = v > 0.f ? v : 0.f;
}

// ---------------------------------------------------------------------------
// K6b: layer 3 finalize: mean over heads + b3, then softmax over 16 classes
// ---------------------------------------------------------------------------
__global__ __launch_bounds__(256) void finalize3(
    const float* __restrict__ acc, const float* __restrict__ denom,
    const float* __restrict__ b, float* __restrict__ out, int n)
{
    int node = blockIdx.x * 16 + (int)threadIdx.x / 16;
    int f = (int)threadIdx.x % 16;
    if (node >= n) return;
    float v0 = acc[(size_t)node * 32 + f]      / (denom[node * 2 + 0] + 1e-16f);
    float v1 = acc[(size_t)node * 32 + 16 + f] / (denom[node * 2 + 1] + 1e-16f);
    float v = 0.5f * (v0 + v1) + b[f];
    float mx = v;
#pragma unroll
    for (int off = 8; off > 0; off >>= 1) mx = fmaxf(mx, __shfl_xor(mx, off, 64));
    float ex = expf(v - mx);
    float sum = ex;
#pragma unroll
    for (int off = 8; off > 0; off >>= 1) sum += __shfl_xor(sum, off, 64);
    out[(size_t)node * 16 + f] = ex / sum;
}

// ---------------------------------------------------------------------------
extern "C" void kernel_launch(void* const* d_in, const int* in_sizes, int n_in,
                              void* d_out, int out_size, void* d_ws, size_t ws_size,
                              hipStream_t stream)
{
    const float* feat = (const float*)d_in[0];
    const int*   ei   = (const int*)d_in[1];
    const float* W1 = (const float*)d_in[2];
    const float* a1s = (const float*)d_in[3];
    const float* a1d = (const float*)d_in[4];
    const float* b1 = (const float*)d_in[5];
    const float* W2 = (const float*)d_in[6];
    const float* a2s = (const float*)d_in[7];
    const float* a2d = (const float*)d_in[8];
    const float* b2 = (const float*)d_in[9];
    const float* W3 = (const float*)d_in[10];
    const float* a3s = (const float*)d_in[11];
    const float* a3d = (const float*)d_in[12];
    const float* b3 = (const float*)d_in[13];

    const int N = in_sizes[0] / 64;
    const int E = in_sizes[1] / 2;
    const int* src = ei;
    const int* dst = ei + E;

    // workspace layout (floats)
    float* bufA = (float*)d_ws;                    // N*128  (h)
    float* bufB = bufA + (size_t)N * 128;          // N*128  (x / acc, ping-pong)
    float* als  = bufB + (size_t)N * 128;          // N*2
    float* ald  = als + (size_t)N * 2;             // N*2
    float* mbuf = ald + (size_t)N * 2;             // N*2
    float* denom= mbuf + (size_t)N * 2;            // N*2
    unsigned* maxb = (unsigned*)(denom + (size_t)N * 2); // N*2

    const int n2 = N * 2;
    dim3 blk(256);

    auto run_layer_big = [&](const float* X, int K, const float* W,
                             const float* as_, const float* ad_, const float* b_) {
        // h -> bufA, acc -> bufB (in-place finalize => bufB becomes next x)
        if (K == 64)
            gemm_logits<64, 64><<<(N + 1) / 2, blk, 0, stream>>>(X, W, as_, ad_, bufA, als, ald, N);
        else
            gemm_logits<128, 64><<<(N + 1) / 2, blk, 0, stream>>>(X, W, as_, ad_, bufA, als, ald, N);
        node_init_max<<<(n2 + 255) / 256, blk, 0, stream>>>(als, maxb, n2);
        edge_max<<<(E + 255) / 256, blk, 0, stream>>>(src, dst, als, maxb, E);
        node_selfinit<64><<<(n2 + 3) / 4, blk, 0, stream>>>(als, ald, maxb, mbuf, denom, bufA, bufB, n2);
        edge_scatter<64><<<(E + 3) / 4, blk, 0, stream>>>(src, dst, als, ald, mbuf, denom, bufA, bufB, E);
        finalize_relu<<<(N * 128 + 255) / 256, blk, 0, stream>>>(bufB, denom, b_, N * 128);
    };

    // Layer 1: x = feat (K=64) -> bufB holds x1
    run_layer_big(feat, 64, W1, a1s, a1d, b1);
    // Layer 2: x = bufB (K=128) -> bufB holds x2
    run_layer_big(bufB, 128, W2, a2s, a2d, b2);

    // Layer 3: K=128, F=16, OUT=32; h -> bufA, acc -> bufB (reused after gemm)
    gemm_logits<128, 16><<<(N + 7) / 8, blk, 0, stream>>>(bufB, W3, a3s, a3d, bufA, als, ald, N);
    node_init_max<<<(n2 + 255) / 256, blk, 0, stream>>>(als, maxb, n2);
    edge_max<<<(E + 255) / 256, blk, 0, stream>>>(src, dst, als, maxb, E);
    node_selfinit<16><<<(n2 + 15) / 16, blk, 0, stream>>>(als, ald, maxb, mbuf, denom, bufA, bufB, n2);
    edge_scatter<16><<<(E + 15) / 16, blk, 0, stream>>>(src, dst, als, ald, mbuf, denom, bufA, bufB, E);
    finalize3<<<(N + 15) / 16, blk, 0, stream>>>(bufB, denom, b3, (float*)d_out, N);
}

// Round 2
// 795.205 us; speedup vs baseline: 2.0264x; 2.0264x over previous
//
#include <hip/hip_runtime.h>

#define NEG_SLOPE 0.2f

__device__ __forceinline__ float lrelu(float x) { return x > 0.f ? x : NEG_SLOPE * x; }

// ---------------------------------------------------------------------------
// K1: h = X @ W  (W staged in LDS), plus per-(node,head) logits
// ---------------------------------------------------------------------------
template<int K, int F>
__global__ __launch_bounds__(256) void gemm_logits(
    const float* __restrict__ X, const float* __restrict__ W,
    const float* __restrict__ a_s, const float* __restrict__ a_d,
    float* __restrict__ Hout, float* __restrict__ als, float* __restrict__ ald,
    int n)
{
    constexpr int OUT = 2 * F;
    constexpr int ROWS = 256 / OUT;
    __shared__ float Wl[K * OUT];
    for (int i = threadIdx.x; i < K * OUT; i += 256) Wl[i] = W[i];
    __syncthreads();

    int r = blockIdx.x * ROWS + (int)threadIdx.x / OUT;
    int col = (int)threadIdx.x % OUT;
    if (r >= n) return;

    const float4* xr = (const float4*)(X + (size_t)r * K);
    float acc = 0.f;
#pragma unroll
    for (int k4 = 0; k4 < K / 4; ++k4) {
        float4 xv = xr[k4];
        acc = fmaf(xv.x, Wl[(4 * k4 + 0) * OUT + col], acc);
        acc = fmaf(xv.y, Wl[(4 * k4 + 1) * OUT + col], acc);
        acc = fmaf(xv.z, Wl[(4 * k4 + 2) * OUT + col], acc);
        acc = fmaf(xv.w, Wl[(4 * k4 + 3) * OUT + col], acc);
    }
    Hout[(size_t)r * OUT + col] = acc;

    float ps = acc * a_s[col];
    float pd = acc * a_d[col];
#pragma unroll
    for (int off = F / 2; off > 0; off >>= 1) {
        ps += __shfl_xor(ps, off, 64);
        pd += __shfl_xor(pd, off, 64);
    }
    if ((col % F) == 0) {
        int head = col / F;
        als[r * 2 + head] = ps;
        ald[r * 2 + head] = pd;
    }
}

// ---------------------------------------------------------------------------
// CSR build (edges are identical for all 3 layers -> build once per call)
// ---------------------------------------------------------------------------
__global__ __launch_bounds__(256) void k_zero_int(int* __restrict__ p, int n) {
    int i = blockIdx.x * 256 + threadIdx.x;
    if (i < n) p[i] = 0;
}

__global__ __launch_bounds__(256) void k_hist(const int* __restrict__ dst,
                                              int* __restrict__ deg, int E) {
    int e = blockIdx.x * 256 + threadIdx.x;
    if (e < E) atomicAdd(&deg[dst[e]], 1);
}

__global__ __launch_bounds__(1024) void k_scan(const int* __restrict__ deg,
                                               int* __restrict__ rowptr,
                                               int* __restrict__ cursor, int n) {
    __shared__ int sm[1024];
    int t = threadIdx.x;
    int chunk = (n + 1023) / 1024;
    int b = t * chunk, e = min(n, b + chunk);
    int s = 0;
    for (int i = b; i < e; ++i) s += deg[i];
    sm[t] = s;
    __syncthreads();
    for (int off = 1; off < 1024; off <<= 1) {
        int v = (t >= off) ? sm[t - off] : 0;
        __syncthreads();
        sm[t] += v;
        __syncthreads();
    }
    int run = (t == 0) ? 0 : sm[t - 1];
    for (int i = b; i < e; ++i) {
        rowptr[i] = run;
        cursor[i] = run;
        run += deg[i];
    }
    if (t == 1023) rowptr[n] = sm[1023];
}

__global__ __launch_bounds__(256) void k_scatter(const int* __restrict__ src,
                                                 const int* __restrict__ dst,
                                                 int* __restrict__ cursor,
                                                 int* __restrict__ esorted, int E) {
    int e = blockIdx.x * 256 + threadIdx.x;
    if (e >= E) return;
    int p = atomicAdd(&cursor[dst[e]], 1);
    esorted[p] = src[e];
}

// ---------------------------------------------------------------------------
// K5': per (node,head): CSR gather-aggregate, softmax fully in registers.
//  pass1: max of als over in-edge sources (+self), lanes parallel over edges
//  pass2: chunked — lane j computes w for edge base+j, then F-step broadcast
//         loop accumulates w_i * h[src_i, head, lane]
//  RELU=true: epilogue x = relu(acc/den + b) fused (layers 1,2)
//  RELU=false: write acc and den (layer 3, finalize3 does mean+softmax)
// ---------------------------------------------------------------------------
template<int F, bool RELU>
__global__ __launch_bounds__(256) void gat_aggregate(
    const int* __restrict__ rowptr, const int* __restrict__ esrc,
    const float* __restrict__ als, const float* __restrict__ ald,
    const float* __restrict__ H, const float* __restrict__ bias,
    float* __restrict__ out, float* __restrict__ denom, int n2)
{
    int g = blockIdx.x * (256 / F) + (int)threadIdx.x / F;
    int lane = (int)threadIdx.x % F;
    if (g >= n2) return;
    int node = g >> 1, head = g & 1;

    float alsd = als[g], aldd = ald[g];
    int beg = rowptr[node], end = rowptr[node + 1];

    // pass 1: segment max (leaky_relu monotone => lrelu(max als[s] + ald))
    float mx = alsd;  // self-loop
    for (int i = beg + lane; i < end; i += F)
        mx = fmaxf(mx, als[esrc[i] * 2 + head]);
#pragma unroll
    for (int off = F / 2; off > 0; off >>= 1)
        mx = fmaxf(mx, __shfl_xor(mx, off, 64));
    float m = lrelu(mx + aldd);

    float wself = expf(lrelu(alsd + aldd) - m);
    float acc = wself * H[(size_t)g * F + lane];
    float den = 0.f;

    int wl = (int)threadIdx.x & 63;
    int gb = wl & ~(F - 1);  // lane index of group start within the wave

    for (int base = beg; base < end; base += F) {
        int cnt = min(F, end - base);
        int s = 0;
        float w = 0.f;
        if (lane < cnt) {
            s = esrc[base + lane];
            w = expf(lrelu(als[s * 2 + head] + aldd) - m);
        }
        den += w;
        for (int i = 0; i < cnt; ++i) {
            int si = __shfl(s, gb + i, 64);
            float wi = __shfl(w, gb + i, 64);
            acc = fmaf(wi, H[((size_t)si * 2 + head) * F + lane], acc);
        }
    }
#pragma unroll
    for (int off = F / 2; off > 0; off >>= 1)
        den += __shfl_xor(den, off, 64);
    den += wself;

    if (RELU) {
        float v = acc / (den + 1e-16f) + bias[head * F + lane];
        out[(size_t)g * F + lane] = v > 0.f ? v : 0.f;
    } else {
        out[(size_t)g * F + lane] = acc;
        if (lane == 0) denom[g] = den;
    }
}

// ---------------------------------------------------------------------------
// K6b: layer 3 finalize: mean over heads + b3, then softmax over 16 classes
// ---------------------------------------------------------------------------
__global__ __launch_bounds__(256) void finalize3(
    const float* __restrict__ acc, const float* __restrict__ denom,
    const float* __restrict__ b, float* __restrict__ out, int n)
{
    int node = blockIdx.x * 16 + (int)threadIdx.x / 16;
    int f = (int)threadIdx.x % 16;
    if (node >= n) return;
    float v0 = acc[(size_t)node * 32 + f]      / (denom[node * 2 + 0] + 1e-16f);
    float v1 = acc[(size_t)node * 32 + 16 + f] / (denom[node * 2 + 1] + 1e-16f);
    float v = 0.5f * (v0 + v1) + b[f];
    float mx = v;
#pragma unroll
    for (int off = 8; off > 0; off >>= 1) mx = fmaxf(mx, __shfl_xor(mx, off, 64));
    float ex = expf(v - mx);
    float sum = ex;
#pragma unroll
    for (int off = 8; off > 0; off >>= 1) sum += __shfl_xor(sum, off, 64);
    out[(size_t)node * 16 + f] = ex / sum;
}

// ---------------------------------------------------------------------------
extern "C" void kernel_launch(void* const* d_in, const int* in_sizes, int n_in,
                              void* d_out, int out_size, void* d_ws, size_t ws_size,
                              hipStream_t stream)
{
    const float* feat = (const float*)d_in[0];
    const int*   ei   = (const int*)d_in[1];
    const float* W1 = (const float*)d_in[2];
    const float* a1s = (const float*)d_in[3];
    const float* a1d = (const float*)d_in[4];
    const float* b1 = (const float*)d_in[5];
    const float* W2 = (const float*)d_in[6];
    const float* a2s = (const float*)d_in[7];
    const float* a2d = (const float*)d_in[8];
    const float* b2 = (const float*)d_in[9];
    const float* W3 = (const float*)d_in[10];
    const float* a3s = (const float*)d_in[11];
    const float* a3d = (const float*)d_in[12];
    const float* b3 = (const float*)d_in[13];

    const int N = in_sizes[0] / 64;
    const int E = in_sizes[1] / 2;
    const int* src = ei;
    const int* dst = ei + E;
    const int n2 = N * 2;

    // workspace layout
    float* bufA  = (float*)d_ws;                    // N*128 (h)
    float* bufB  = bufA + (size_t)N * 128;          // N*128 (x / acc)
    float* als   = bufB + (size_t)N * 128;          // N*2
    float* ald   = als + (size_t)n2;                // N*2
    float* denom = ald + (size_t)n2;                // N*2
    int* deg     = (int*)(denom + (size_t)n2);      // N
    int* rowptr  = deg + N;                         // N+1
    int* cursor  = rowptr + (N + 1);                // N
    int* esorted = cursor + N;                      // E

    dim3 blk(256);

    // --- build CSR by dst (once; shared by all 3 layers) ---
    k_zero_int<<<(N + 255) / 256, blk, 0, stream>>>(deg, N);
    k_hist<<<(E + 255) / 256, blk, 0, stream>>>(dst, deg, E);
    k_scan<<<1, 1024, 0, stream>>>(deg, rowptr, cursor, N);
    k_scatter<<<(E + 255) / 256, blk, 0, stream>>>(src, dst, cursor, esorted, E);

    // --- layer 1 (K=64) ---
    gemm_logits<64, 64><<<(N + 1) / 2, blk, 0, stream>>>(feat, W1, a1s, a1d, bufA, als, ald, N);
    gat_aggregate<64, true><<<(n2 + 3) / 4, blk, 0, stream>>>(
        rowptr, esorted, als, ald, bufA, b1, bufB, nullptr, n2);

    // --- layer 2 (K=128) ---
    gemm_logits<128, 64><<<(N + 1) / 2, blk, 0, stream>>>(bufB, W2, a2s, a2d, bufA, als, ald, N);
    gat_aggregate<64, true><<<(n2 + 3) / 4, blk, 0, stream>>>(
        rowptr, esorted, als, ald, bufA, b2, bufB, nullptr, n2);

    // --- layer 3 (K=128, F=16) ---
    gemm_logits<128, 16><<<(N + 7) / 8, blk, 0, stream>>>(bufB, W3, a3s, a3d, bufA, als, ald, N);
    gat_aggregate<16, false><<<(n2 + 15) / 16, blk, 0, stream>>>(
        rowptr, esorted, als, ald, bufA, nullptr, bufB, denom, n2);
    finalize3<<<(N + 15) / 16, blk, 0, stream>>>(bufB, denom, b3, (float*)d_out, N);
}

// Round 3
// 559.511 us; speedup vs baseline: 2.8800x; 1.4212x over previous
//
#include <hip/hip_runtime.h>

#define NEG_SLOPE 0.2f

__device__ __forceinline__ float lrelu(float x) { return x > 0.f ? x : NEG_SLOPE * x; }

// ---------------------------------------------------------------------------
// K1: h = X @ W (register-tiled) + per-(node,head) attention logits.
// 256 threads = TX x TY; thread computes MR=8 rows x 4 cols (float4 acc).
// K chunked at KC=32: Xs[BM][KC] + Ws[KC][OUT] staged in LDS.
// ---------------------------------------------------------------------------
template<int K, int OUT, int F>
__global__ __launch_bounds__(256) void gemm_logits(
    const float* __restrict__ X, const float* __restrict__ W,
    const float* __restrict__ a_s, const float* __restrict__ a_d,
    float* __restrict__ Hout, float* __restrict__ als, float* __restrict__ ald,
    int n)
{
    constexpr int TX = OUT / 4;      // col-threads (one float4 each)
    constexpr int TY = 256 / TX;     // row-threads
    constexpr int MR = 8;            // rows per thread
    constexpr int BM = TY * MR;      // rows per block
    constexpr int KC = 32;           // k-chunk

    __shared__ __align__(16) float Xs[BM][KC];
    __shared__ __align__(16) float Ws[KC][OUT];

    const int tx = (int)threadIdx.x % TX;
    const int ty = (int)threadIdx.x / TX;
    const int r0 = blockIdx.x * BM;

    float4 acc[MR];
#pragma unroll
    for (int m = 0; m < MR; ++m) acc[m] = make_float4(0.f, 0.f, 0.f, 0.f);

    for (int kc = 0; kc < K; kc += KC) {
        __syncthreads();
        // cooperative load of X tile (zero-padded past n)
        constexpr int XV = BM * KC / 4;
#pragma unroll
        for (int i = threadIdx.x; i < XV; i += 256) {
            int f = i * 4;
            int r = f / KC, k = f % KC;
            int gr = r0 + r;
            float4 v = make_float4(0.f, 0.f, 0.f, 0.f);
            if (gr < n) v = *(const float4*)(X + (size_t)gr * K + kc + k);
            *(float4*)(&Xs[r][k]) = v;
        }
        // cooperative load of W chunk
        constexpr int WV = KC * OUT / 4;
#pragma unroll
        for (int i = threadIdx.x; i < WV; i += 256) {
            int f = i * 4;
            int k = f / OUT, c = f % OUT;
            *(float4*)(&Ws[k][c]) = *(const float4*)(W + (size_t)(kc + k) * OUT + c);
        }
        __syncthreads();

#pragma unroll
        for (int k4 = 0; k4 < KC; k4 += 4) {
            float4 xv[MR];
#pragma unroll
            for (int m = 0; m < MR; ++m)
                xv[m] = *(const float4*)(&Xs[ty * MR + m][k4]);
#pragma unroll
            for (int kk = 0; kk < 4; ++kk) {
                float4 wv = *(const float4*)(&Ws[k4 + kk][tx * 4]);
#pragma unroll
                for (int m = 0; m < MR; ++m) {
                    float xm = kk == 0 ? xv[m].x : kk == 1 ? xv[m].y : kk == 2 ? xv[m].z : xv[m].w;
                    acc[m].x = fmaf(xm, wv.x, acc[m].x);
                    acc[m].y = fmaf(xm, wv.y, acc[m].y);
                    acc[m].z = fmaf(xm, wv.z, acc[m].z);
                    acc[m].w = fmaf(xm, wv.w, acc[m].w);
                }
            }
        }
    }

    // epilogue: store H, compute logit partials and reduce across the head's tx-lanes
    const float4 asv = *(const float4*)(a_s + tx * 4);
    const float4 adv = *(const float4*)(a_d + tx * 4);
    constexpr int UH = F / 4;           // tx-lanes per head
    const int head = tx / UH;
#pragma unroll
    for (int m = 0; m < MR; ++m) {
        int gr = r0 + ty * MR + m;
        float ps = acc[m].x * asv.x + acc[m].y * asv.y + acc[m].z * asv.z + acc[m].w * asv.w;
        float pd = acc[m].x * adv.x + acc[m].y * adv.y + acc[m].z * adv.z + acc[m].w * adv.w;
#pragma unroll
        for (int off = UH / 2; off > 0; off >>= 1) {
            ps += __shfl_xor(ps, off, 64);
            pd += __shfl_xor(pd, off, 64);
        }
        if (gr < n) {
            *(float4*)(Hout + (size_t)gr * OUT + tx * 4) = acc[m];
            if ((tx % UH) == 0) {
                als[gr * 2 + head] = ps;
                ald[gr * 2 + head] = pd;
            }
        }
    }
}

// ---------------------------------------------------------------------------
// CSR build (edges identical for all 3 layers -> build once per call)
// ---------------------------------------------------------------------------
__global__ __launch_bounds__(256) void k_zero_int(int* __restrict__ p, int n) {
    int i = blockIdx.x * 256 + threadIdx.x;
    if (i < n) p[i] = 0;
}

__global__ __launch_bounds__(256) void k_hist(const int* __restrict__ dst,
                                              int* __restrict__ deg, int E) {
    int e = blockIdx.x * 256 + threadIdx.x;
    if (e < E) atomicAdd(&deg[dst[e]], 1);
}

__global__ __launch_bounds__(1024) void k_scan(const int* __restrict__ deg,
                                               int* __restrict__ rowptr,
                                               int* __restrict__ cursor, int n) {
    __shared__ int sm[1024];
    int t = threadIdx.x;
    int chunk = (n + 1023) / 1024;
    int b = t * chunk, e = min(n, b + chunk);
    int s = 0;
    for (int i = b; i < e; ++i) s += deg[i];
    sm[t] = s;
    __syncthreads();
    for (int off = 1; off < 1024; off <<= 1) {
        int v = (t >= off) ? sm[t - off] : 0;
        __syncthreads();
        sm[t] += v;
        __syncthreads();
    }
    int run = (t == 0) ? 0 : sm[t - 1];
    for (int i = b; i < e; ++i) {
        rowptr[i] = run;
        cursor[i] = run;
        run += deg[i];
    }
    if (t == 1023) rowptr[n] = sm[1023];
}

__global__ __launch_bounds__(256) void k_scatter(const int* __restrict__ src,
                                                 const int* __restrict__ dst,
                                                 int* __restrict__ cursor,
                                                 int* __restrict__ esorted, int E) {
    int e = blockIdx.x * 256 + threadIdx.x;
    if (e >= E) return;
    int p = atomicAdd(&cursor[dst[e]], 1);
    esorted[p] = src[e];
}

// ---------------------------------------------------------------------------
// K5': per (node,head): CSR gather-aggregate, softmax fully in registers.
// ---------------------------------------------------------------------------
template<int F, bool RELU>
__global__ __launch_bounds__(256) void gat_aggregate(
    const int* __restrict__ rowptr, const int* __restrict__ esrc,
    const float* __restrict__ als, const float* __restrict__ ald,
    const float* __restrict__ H, const float* __restrict__ bias,
    float* __restrict__ out, float* __restrict__ denom, int n2)
{
    int g = blockIdx.x * (256 / F) + (int)threadIdx.x / F;
    int lane = (int)threadIdx.x % F;
    if (g >= n2) return;
    int node = g >> 1, head = g & 1;

    float alsd = als[g], aldd = ald[g];
    int beg = rowptr[node], end = rowptr[node + 1];

    // pass 1: segment max (leaky_relu monotone)
    float mx = alsd;  // self-loop
    for (int i = beg + lane; i < end; i += F)
        mx = fmaxf(mx, als[esrc[i] * 2 + head]);
#pragma unroll
    for (int off = F / 2; off > 0; off >>= 1)
        mx = fmaxf(mx, __shfl_xor(mx, off, 64));
    float m = lrelu(mx + aldd);

    float wself = expf(lrelu(alsd + aldd) - m);
    float acc = wself * H[(size_t)g * F + lane];
    float den = 0.f;

    int wl = (int)threadIdx.x & 63;
    int gb = wl & ~(F - 1);

    for (int base = beg; base < end; base += F) {
        int cnt = min(F, end - base);
        int s = 0;
        float w = 0.f;
        if (lane < cnt) {
            s = esrc[base + lane];
            w = expf(lrelu(als[s * 2 + head] + aldd) - m);
        }
        den += w;
        for (int i = 0; i < cnt; ++i) {
            int si = __shfl(s, gb + i, 64);
            float wi = __shfl(w, gb + i, 64);
            acc = fmaf(wi, H[((size_t)si * 2 + head) * F + lane], acc);
        }
    }
#pragma unroll
    for (int off = F / 2; off > 0; off >>= 1)
        den += __shfl_xor(den, off, 64);
    den += wself;

    if (RELU) {
        float v = acc / (den + 1e-16f) + bias[head * F + lane];
        out[(size_t)g * F + lane] = v > 0.f ? v : 0.f;
    } else {
        out[(size_t)g * F + lane] = acc;
        if (lane == 0) denom[g] = den;
    }
}

// ---------------------------------------------------------------------------
// K6b: layer 3 finalize: mean over heads + b3, softmax over 16 classes
// ---------------------------------------------------------------------------
__global__ __launch_bounds__(256) void finalize3(
    const float* __restrict__ acc, const float* __restrict__ denom,
    const float* __restrict__ b, float* __restrict__ out, int n)
{
    int node = blockIdx.x * 16 + (int)threadIdx.x / 16;
    int f = (int)threadIdx.x % 16;
    if (node >= n) return;
    float v0 = acc[(size_t)node * 32 + f]      / (denom[node * 2 + 0] + 1e-16f);
    float v1 = acc[(size_t)node * 32 + 16 + f] / (denom[node * 2 + 1] + 1e-16f);
    float v = 0.5f * (v0 + v1) + b[f];
    float mx = v;
#pragma unroll
    for (int off = 8; off > 0; off >>= 1) mx = fmaxf(mx, __shfl_xor(mx, off, 64));
    float ex = expf(v - mx);
    float sum = ex;
#pragma unroll
    for (int off = 8; off > 0; off >>= 1) sum += __shfl_xor(sum, off, 64);
    out[(size_t)node * 16 + f] = ex / sum;
}

// ---------------------------------------------------------------------------
extern "C" void kernel_launch(void* const* d_in, const int* in_sizes, int n_in,
                              void* d_out, int out_size, void* d_ws, size_t ws_size,
                              hipStream_t stream)
{
    const float* feat = (const float*)d_in[0];
    const int*   ei   = (const int*)d_in[1];
    const float* W1 = (const float*)d_in[2];
    const float* a1s = (const float*)d_in[3];
    const float* a1d = (const float*)d_in[4];
    const float* b1 = (const float*)d_in[5];
    const float* W2 = (const float*)d_in[6];
    const float* a2s = (const float*)d_in[7];
    const float* a2d = (const float*)d_in[8];
    const float* b2 = (const float*)d_in[9];
    const float* W3 = (const float*)d_in[10];
    const float* a3s = (const float*)d_in[11];
    const float* a3d = (const float*)d_in[12];
    const float* b3 = (const float*)d_in[13];

    const int N = in_sizes[0] / 64;
    const int E = in_sizes[1] / 2;
    const int* src = ei;
    const int* dst = ei + E;
    const int n2 = N * 2;

    // workspace layout
    float* bufA  = (float*)d_ws;                    // N*128 (h)
    float* bufB  = bufA + (size_t)N * 128;          // N*128 (x / acc)
    float* als   = bufB + (size_t)N * 128;          // N*2
    float* ald   = als + (size_t)n2;                // N*2
    float* denom = ald + (size_t)n2;                // N*2
    int* deg     = (int*)(denom + (size_t)n2);      // N
    int* rowptr  = deg + N;                         // N+1
    int* cursor  = rowptr + (N + 1);                // N
    int* esorted = cursor + N;                      // E

    dim3 blk(256);

    // --- build CSR by dst (once; shared by all 3 layers) ---
    k_zero_int<<<(N + 255) / 256, blk, 0, stream>>>(deg, N);
    k_hist<<<(E + 255) / 256, blk, 0, stream>>>(dst, deg, E);
    k_scan<<<1, 1024, 0, stream>>>(deg, rowptr, cursor, N);
    k_scatter<<<(E + 255) / 256, blk, 0, stream>>>(src, dst, cursor, esorted, E);

    // --- layer 1 (K=64, OUT=128) ---
    gemm_logits<64, 128, 64><<<(N + 63) / 64, blk, 0, stream>>>(feat, W1, a1s, a1d, bufA, als, ald, N);
    gat_aggregate<64, true><<<(n2 + 3) / 4, blk, 0, stream>>>(
        rowptr, esorted, als, ald, bufA, b1, bufB, nullptr, n2);

    // --- layer 2 (K=128, OUT=128) ---
    gemm_logits<128, 128, 64><<<(N + 63) / 64, blk, 0, stream>>>(bufB, W2, a2s, a2d, bufA, als, ald, N);
    gat_aggregate<64, true><<<(n2 + 3) / 4, blk, 0, stream>>>(
        rowptr, esorted, als, ald, bufA, b2, bufB, nullptr, n2);

    // --- layer 3 (K=128, OUT=32, F=16) ---
    gemm_logits<128, 32, 16><<<(N + 255) / 256, blk, 0, stream>>>(bufB, W3, a3s, a3d, bufA, als, ald, N);
    gat_aggregate<16, false><<<(n2 + 15) / 16, blk, 0, stream>>>(
        rowptr, esorted, als, ald, bufA, nullptr, bufB, denom, n2);
    finalize3<<<(N + 15) / 16, blk, 0, stream>>>(bufB, denom, b3, (float*)d_out, N);
}